// Round 5
// baseline (11994.543 us; speedup 1.0000x reference)
//
#include <hip/hip_runtime.h>
#include <math.h>

#define HDIM 256
#define BATCH 64
#define TLEN 512
#define IDIM 64

typedef __attribute__((ext_vector_type(8))) short s16x8;
typedef __attribute__((ext_vector_type(4))) float f32x4;

// ---------------- ws layout (float offsets) ----------------
static const size_t OFF_XG    = 0;
static const size_t OFF_YA    = 33554432;
static const size_t OFF_YB    = OFF_YA + 8388608;
static const size_t OFF_WIHT  = OFF_YB + 8388608;
static const size_t OFF_WHI   = OFF_WIHT + 1048576;
static const size_t OFF_WLO   = OFF_WHI + 524288;
static const size_t OFF_BSUM  = OFF_WLO + 524288;
static const size_t OFF_STATE = OFF_BSUM + 4096;
static const size_t OFF_HXP   = OFF_STATE + 65536;   // [2 parity][64][256] u32 packed
static const size_t OFF_CTR   = OFF_HXP + 32768;

__device__ __forceinline__ float sig_(float x) { return 1.f / (1.f + __expf(-x)); }
__device__ __forceinline__ float tanh_(float x) { float e = __expf(2.f * x); return 1.f - 2.f / (e + 1.f); }

// RNE fp32 -> bf16 hi + bf16 lo, packed (hi<<16)|lo.
__device__ __forceinline__ unsigned int packhl(float h) {
    unsigned int u = __float_as_uint(h);
    unsigned int hb = (u + 0x7fffu + ((u >> 16) & 1u)) >> 16;
    float r = h - __uint_as_float(hb << 16);
    unsigned int ur = __float_as_uint(r);
    unsigned int lb = (ur + 0x7fffu + ((ur >> 16) & 1u)) >> 16;
    return (hb << 16) | (lb & 0xffffu);
}

__device__ __forceinline__ void st_llc(unsigned int* p, unsigned int v) {
    __hip_atomic_store(p, v, __ATOMIC_RELAXED, __HIP_MEMORY_SCOPE_AGENT);
}
__device__ __forceinline__ unsigned long long ld_llc8(const unsigned int* p) {
    return __hip_atomic_load((const unsigned long long*)p, __ATOMIC_RELAXED, __HIP_MEMORY_SCOPE_AGENT);
}

// -------- prep --------
__global__ void prep_wih(const float* __restrict__ w, float* __restrict__ wt, int K) {
    int idx = blockIdx.x * 256 + threadIdx.x;
    if (idx >= 1024 * K) return;
    int n = idx / K, k = idx - n * K;
    int j = n >> 2, g = n & 3;
    wt[idx] = w[(g * 256 + j) * K + k];
}

__global__ void prep_whh_split(const float* __restrict__ w,
                               unsigned short* __restrict__ hi, unsigned short* __restrict__ lo) {
    int idx = blockIdx.x * 256 + threadIdx.x;
    float v = w[idx];
    unsigned int u = __float_as_uint(v);
    unsigned int hb = (u + 0x7fffu + ((u >> 16) & 1u)) >> 16;
    float r = v - __uint_as_float(hb << 16);
    unsigned int ur = __float_as_uint(r);
    unsigned int lb = (ur + 0x7fffu + ((ur >> 16) & 1u)) >> 16;
    hi[idx] = (unsigned short)hb;
    lo[idx] = (unsigned short)lb;
}

__global__ void prep_bias(const float* __restrict__ bi, const float* __restrict__ bh,
                          float* __restrict__ bs) {
    int n = blockIdx.x * 256 + threadIdx.x;
    int j = n >> 2, g = n & 3;
    bs[n] = bi[g * 256 + j] + bh[g * 256 + j];
}

// -------- projection GEMM --------
__global__ __launch_bounds__(256) void proj_kernel(
    const float* __restrict__ A, int K, int doRelu,
    const float* __restrict__ Wt, const float* __restrict__ bsum,
    float* __restrict__ out)
{
    __shared__ float As[16][128];
    __shared__ float Bs[16][128];
    const int tid = threadIdx.x;
    const int m0 = blockIdx.x * 128;
    const int n0 = blockIdx.y * 128;
    const int tx = tid & 15, ty = tid >> 4;

    float acc[8][8];
#pragma unroll
    for (int i = 0; i < 8; ++i)
#pragma unroll
        for (int j = 0; j < 8; ++j) acc[i][j] = 0.f;

    for (int kt = 0; kt < K; kt += 16) {
#pragma unroll
        for (int l = 0; l < 2; ++l) {
            int f = tid * 2 + l;
            int r = f >> 2;
            int c = (f & 3) << 2;
            float4 v = *(const float4*)&A[(size_t)(m0 + r) * K + kt + c];
            if (doRelu) {
                v.x = fmaxf(v.x, 0.f); v.y = fmaxf(v.y, 0.f);
                v.z = fmaxf(v.z, 0.f); v.w = fmaxf(v.w, 0.f);
            }
            As[c + 0][r] = v.x; As[c + 1][r] = v.y; As[c + 2][r] = v.z; As[c + 3][r] = v.w;
            float4 w = *(const float4*)&Wt[(size_t)(n0 + r) * K + kt + c];
            Bs[c + 0][r] = w.x; Bs[c + 1][r] = w.y; Bs[c + 2][r] = w.z; Bs[c + 3][r] = w.w;
        }
        __syncthreads();
#pragma unroll
        for (int kk = 0; kk < 16; ++kk) {
            float a[8], bb[8];
            *(float4*)&a[0]  = *(const float4*)&As[kk][ty * 8];
            *(float4*)&a[4]  = *(const float4*)&As[kk][ty * 8 + 4];
            *(float4*)&bb[0] = *(const float4*)&Bs[kk][tx * 8];
            *(float4*)&bb[4] = *(const float4*)&Bs[kk][tx * 8 + 4];
#pragma unroll
            for (int i = 0; i < 8; ++i)
#pragma unroll
                for (int j = 0; j < 8; ++j) acc[i][j] = fmaf(a[i], bb[j], acc[i][j]);
        }
        __syncthreads();
    }

    float bsv[8];
#pragma unroll
    for (int j = 0; j < 8; ++j) bsv[j] = bsum[n0 + tx * 8 + j];
#pragma unroll
    for (int i = 0; i < 8; ++i) {
        size_t row = (size_t)(m0 + ty * 8 + i);
        float4 o1 = { acc[i][0] + bsv[0], acc[i][1] + bsv[1], acc[i][2] + bsv[2], acc[i][3] + bsv[3] };
        float4 o2 = { acc[i][4] + bsv[4], acc[i][5] + bsv[5], acc[i][6] + bsv[6], acc[i][7] + bsv[7] };
        *(float4*)&out[row * 1024 + n0 + tx * 8]     = o1;
        *(float4*)&out[row * 1024 + n0 + tx * 8 + 4] = o2;
    }
}

// -------- cooperative persistent-weight recurrence v3 --------
// 16 WGs x 256 thr. group gid = bid&3 (16 batches), j-slice wgj = bid>>2 (64 j).
// Wave w covers j-cols [jw, jw+16) for ALL 4 gates: weights bhi/blo[4][8] in
// VGPRs (256 regs). MFMA C-layout (col=lane&15=j, row=l4*4+r=b) puts all 4
// gates of a (b,j) in ONE lane -> in-lane nonlinearity, no LDS exchange.
// All per-step global accesses coalesced: lane owns (b=bbase+l4*4+r, j=jw+l15).
// hxp packed-u32 LLC-atomic protocol as round 4; y = plain store after flag.
__global__ __launch_bounds__(256, 1) void rec_coop(
    const float* __restrict__ xg4,
    const unsigned short* __restrict__ whi, const unsigned short* __restrict__ wlo,
    float* __restrict__ y,
    const float* __restrict__ h_init, const float* __restrict__ c_init,
    float* __restrict__ h_save, float* __restrict__ c_save,
    unsigned int* __restrict__ hxp, int* __restrict__ ctr)
{
    const int tid  = threadIdx.x;
    const int lane = tid & 63;
    const int w    = tid >> 6;
    const int gid  = blockIdx.x & 3;
    const int wgj  = blockIdx.x >> 2;
    const int bbase = gid * 16;
    const int jw   = wgj * 64 + w * 16;
    const int l15 = lane & 15, l4 = lane >> 4;
    const int ob = bbase + l4 * 4;          // lane's batch base (r = 0..3)
    int* cnt = ctr + gid * 513;

    // persistent weights: [gate][ktile], 256 VGPRs
    s16x8 bhi[4][8], blo[4][8];
#pragma unroll
    for (int g = 0; g < 4; ++g) {
        size_t rb = (size_t)(g * 256 + jw + l15) * 256 + l4 * 8;
#pragma unroll
        for (int kt = 0; kt < 8; ++kt) {
            bhi[g][kt] = *(const s16x8*)(whi + rb + kt * 32);
            blo[g][kt] = *(const s16x8*)(wlo + rb + kt * 32);
        }
    }

    float c[4], h[4];
#pragma unroll
    for (int r = 0; r < 4; ++r) { c[r] = 0.f; h[r] = 0.f; }
    if (h_init != nullptr) {
#pragma unroll
        for (int r = 0; r < 4; ++r) {
            h[r] = h_init[(ob + r) * 256 + jw + l15];
            c[r] = c_init[(ob + r) * 256 + jw + l15];
        }
    }
    // publish h_0 into parity 0 (coalesced: 16 lanes -> 64B)
#pragma unroll
    for (int r = 0; r < 4; ++r)
        st_llc(&hxp[(size_t)(ob + r) * 256 + jw + l15], packhl(h[r]));
    __syncthreads();
    if (tid == 0)
        __hip_atomic_fetch_add(&cnt[0], 1, __ATOMIC_RELAXED, __HIP_MEMORY_SCOPE_AGENT);

    for (int t = 0; t < TLEN; ++t) {
        // own (b,j) x-gates: independent of handshake, issue before the spin
        float4 xv[4];
#pragma unroll
        for (int r = 0; r < 4; ++r)
            xv[r] = *(const float4*)&xg4[((size_t)(ob + r) * TLEN + t) * 1024 + (jw + l15) * 4];

        if (tid == 0) {
            while (__hip_atomic_load(&cnt[t], __ATOMIC_RELAXED, __HIP_MEMORY_SCOPE_AGENT) < 4)
                __builtin_amdgcn_s_sleep(1);
        }
        __syncthreads();
        asm volatile("" ::: "memory");

        const unsigned int* hp = hxp + (size_t)(t & 1) * 16384
                                 + (size_t)(bbase + l15) * 256 + l4 * 8;

        f32x4 aH[4], aC[4];
#pragma unroll
        for (int g = 0; g < 4; ++g) { aH[g] = (f32x4){0,0,0,0}; aC[g] = (f32x4){0,0,0,0}; }

#pragma unroll
        for (int kt = 0; kt < 8; ++kt) {
            unsigned long long q0 = ld_llc8(hp + kt * 32 + 0);
            unsigned long long q1 = ld_llc8(hp + kt * 32 + 2);
            unsigned long long q2 = ld_llc8(hp + kt * 32 + 4);
            unsigned long long q3 = ld_llc8(hp + kt * 32 + 6);
            unsigned int w0 = (unsigned int)q0, w1 = (unsigned int)(q0 >> 32);
            unsigned int w2 = (unsigned int)q1, w3 = (unsigned int)(q1 >> 32);
            unsigned int w4 = (unsigned int)q2, w5 = (unsigned int)(q2 >> 32);
            unsigned int w6 = (unsigned int)q3, w7 = (unsigned int)(q3 >> 32);
            union { unsigned int u[4]; s16x8 v; } ah, al;
            ah.u[0] = (w0 >> 16) | (w1 & 0xffff0000u);
            ah.u[1] = (w2 >> 16) | (w3 & 0xffff0000u);
            ah.u[2] = (w4 >> 16) | (w5 & 0xffff0000u);
            ah.u[3] = (w6 >> 16) | (w7 & 0xffff0000u);
            al.u[0] = (w0 & 0xffffu) | (w1 << 16);
            al.u[1] = (w2 & 0xffffu) | (w3 << 16);
            al.u[2] = (w4 & 0xffffu) | (w5 << 16);
            al.u[3] = (w6 & 0xffffu) | (w7 << 16);
#pragma unroll
            for (int g = 0; g < 4; ++g) {
                aH[g] = __builtin_amdgcn_mfma_f32_16x16x32_bf16(ah.v, bhi[g][kt], aH[g], 0, 0, 0);
                aC[g] = __builtin_amdgcn_mfma_f32_16x16x32_bf16(al.v, bhi[g][kt], aC[g], 0, 0, 0);
                aC[g] = __builtin_amdgcn_mfma_f32_16x16x32_bf16(ah.v, blo[g][kt], aC[g], 0, 0, 0);
            }
        }

        // in-lane nonlinearity for the 4 (b,j) pairs this lane owns
        size_t hb2 = (size_t)((t + 1) & 1) * 16384;
#pragma unroll
        for (int r = 0; r < 4; ++r) {
            float si = aH[0][r] + aC[0][r] + xv[r].x;
            float sf = aH[1][r] + aC[1][r] + xv[r].y;
            float sg = aH[2][r] + aC[2][r] + xv[r].z;
            float so = aH[3][r] + aC[3][r] + xv[r].w;
            float ig = sig_(si);
            float fg = sig_(sf);
            float gg = tanh_(sg);
            float og = sig_(so);
            c[r] = fmaf(fg, c[r], ig * gg);
            h[r] = og * tanh_(c[r]);
            st_llc(&hxp[hb2 + (size_t)(ob + r) * 256 + jw + l15], packhl(h[r]));
        }

        __syncthreads();   // vmcnt(0): h publishes ack'd at LLC
        asm volatile("" ::: "memory");
        if (tid == 0)
            __hip_atomic_fetch_add(&cnt[t + 1], 1, __ATOMIC_RELAXED, __HIP_MEMORY_SCOPE_AGENT);

        // y: plain cached stores, off the critical drain (coalesced 64B/16 lanes)
#pragma unroll
        for (int r = 0; r < 4; ++r)
            y[((size_t)(ob + r) * TLEN + t) * 256 + jw + l15] = h[r];
    }

    if (h_save != nullptr) {
#pragma unroll
        for (int r = 0; r < 4; ++r) {
            h_save[(ob + r) * 256 + jw + l15] = h[r];
            c_save[(ob + r) * 256 + jw + l15] = c[r];
        }
    }
}

// -------- head --------
__global__ __launch_bounds__(256) void head_kernel(const float* __restrict__ y3,
    const float* __restrict__ lin_w, const float* __restrict__ lin_b, float* __restrict__ out)
{
    int b = blockIdx.x;
    int tid = threadIdx.x;
    float v = y3[((size_t)b * TLEN + (TLEN - 1)) * HDIM + tid] * lin_w[tid];
#pragma unroll
    for (int o = 32; o > 0; o >>= 1) v += __shfl_down(v, o);
    __shared__ float red[4];
    int wid = tid >> 6, lane = tid & 63;
    if (lane == 0) red[wid] = v;
    __syncthreads();
    if (tid == 0) out[b] = red[0] + red[1] + red[2] + red[3] + lin_b[0];
}

extern "C" void kernel_launch(void* const* d_in, const int* in_sizes, int n_in,
                              void* d_out, int out_size, void* d_ws, size_t ws_size,
                              hipStream_t stream) {
    const float* x = (const float*)d_in[0];
    const float* wih[4] = { (const float*)d_in[1], (const float*)d_in[5], (const float*)d_in[9],  (const float*)d_in[13] };
    const float* whh[4] = { (const float*)d_in[2], (const float*)d_in[6], (const float*)d_in[10], (const float*)d_in[14] };
    const float* bih[4] = { (const float*)d_in[3], (const float*)d_in[7], (const float*)d_in[11], (const float*)d_in[15] };
    const float* bhh[4] = { (const float*)d_in[4], (const float*)d_in[8], (const float*)d_in[12], (const float*)d_in[16] };
    const float* lin_w = (const float*)d_in[17];
    const float* lin_b = (const float*)d_in[18];
    float* ws = (float*)d_ws;

    float* xg4  = ws + OFF_XG;
    float* yA   = ws + OFF_YA;
    float* yB   = ws + OFF_YB;
    float* wihT = ws + OFF_WIHT;
    unsigned short* whiB = (unsigned short*)(ws + OFF_WHI);
    unsigned short* wloB = (unsigned short*)(ws + OFF_WLO);
    float* bsum = ws + OFF_BSUM;
    float* h0T  = ws + OFF_STATE;
    float* c0T  = h0T + BATCH * HDIM;
    float* h1T  = c0T + BATCH * HDIM;
    float* c1T  = h1T + BATCH * HDIM;
    unsigned int* hxp = (unsigned int*)(ws + OFF_HXP);
    int* ctr = (int*)(ws + OFF_CTR);

    hipMemsetAsync(ctr, 0, 4 * 4 * 513 * sizeof(int), stream);

    for (int l = 0; l < 4; ++l) {
        int K = (l == 0) ? IDIM : HDIM;
        prep_wih<<<dim3((1024 * K + 255) / 256), 256, 0, stream>>>(wih[l], wihT + (size_t)l * 262144, K);
        prep_whh_split<<<dim3(1024), 256, 0, stream>>>(whh[l], whiB + (size_t)l * 262144, wloB + (size_t)l * 262144);
        prep_bias<<<dim3(4), 256, 0, stream>>>(bih[l], bhh[l], bsum + l * 1024);
    }

    dim3 pgrid(256, 8);
    dim3 rgrid(16);

    proj_kernel<<<pgrid, 256, 0, stream>>>(x, IDIM, 1, wihT + 0 * 262144, bsum + 0 * 1024, xg4);
    rec_coop<<<rgrid, 256, 0, stream>>>(xg4, whiB + 0 * 262144, wloB + 0 * 262144, yA,
                                        nullptr, nullptr, h0T, c0T, hxp, ctr + 0 * 2052);

    proj_kernel<<<pgrid, 256, 0, stream>>>(yA, HDIM, 0, wihT + 1 * 262144, bsum + 1 * 1024, xg4);
    rec_coop<<<rgrid, 256, 0, stream>>>(xg4, whiB + 1 * 262144, wloB + 1 * 262144, yB,
                                        nullptr, nullptr, h1T, c1T, hxp, ctr + 1 * 2052);

    proj_kernel<<<pgrid, 256, 0, stream>>>(yB, HDIM, 1, wihT + 2 * 262144, bsum + 2 * 1024, xg4);
    rec_coop<<<rgrid, 256, 0, stream>>>(xg4, whiB + 2 * 262144, wloB + 2 * 262144, yA,
                                        h0T, c0T, nullptr, nullptr, hxp, ctr + 2 * 2052);

    proj_kernel<<<pgrid, 256, 0, stream>>>(yA, HDIM, 0, wihT + 3 * 262144, bsum + 3 * 1024, xg4);
    rec_coop<<<rgrid, 256, 0, stream>>>(xg4, whiB + 3 * 262144, wloB + 3 * 262144, yB,
                                        h1T, c1T, nullptr, nullptr, hxp, ctr + 3 * 2052);

    head_kernel<<<dim3(BATCH), 256, 0, stream>>>(yB, lin_w, lin_b, (float*)d_out);
}